// Round 12
// baseline (109.317 us; speedup 1.0000x reference)
//
#include <hip/hip_runtime.h>

// Problem constants
#define B_ 4
#define E_ 1024
#define S_ 2048
#define H_ 16
#define K_ 1024

#define NCH 32          // scan chunks along S (batch-local)
#define CS  (S_/NCH)    // 64

typedef __bf16 bf16x8 __attribute__((ext_vector_type(8)));
typedef float  f32x4  __attribute__((ext_vector_type(4)));
typedef unsigned short u16x8 __attribute__((ext_vector_type(8)));

#define AS1 __attribute__((address_space(1)))
#define AS3 __attribute__((address_space(3)))
#define SWZ(row) ((((row) >> 1) & 3) << 4)

__device__ __forceinline__ unsigned short f2bf(float f) {
  unsigned u = __float_as_uint(f);
  u += 0x7fffu + ((u >> 16) & 1u);   // round-to-nearest-even
  return (unsigned short)(u >> 16);
}
__device__ __forceinline__ float bf2f(unsigned short h) {
  return __uint_as_float(((unsigned)h) << 16);
}

// ---------------------------------------------------------------------------
// GEMM1 (fused transpose+convert): Yt (8192 x 1024) = x^T_bf16 * W1_bf16^T + b
// Per-buffer LDS layout: A in [0,16384), B in [16384,32768)  (R11 bug: B was
// written at +32768 = other buffer's A region -> NaN; fixed here).
// A staged straight from x (B,E,S) fp32: reg-load 4 float4 (one e-row, 16 s),
// convert, 16 ds_write_u16 into swizzled A-tile (2-way bank alias = free).
// B staged straight from W1 fp32: 4 coalesced float4 + 2 ds_write_b128.
// R9 skeleton: 128x128 tile, BK=64, 512 thr (2Mx4N waves), 64 KB dbuf LDS,
// 1 barrier/tile, loads issued one tile ahead; T1 XCD tiling; 2 blocks/CU.
// Epilogue: Yt bf16 + fused scan chunk partials -> part.
// ---------------------------------------------------------------------------
__global__ __launch_bounds__(512, 4)
void gemm1_fused(const float* __restrict__ x, const float* __restrict__ W1,
                 unsigned short* __restrict__ Yt, const float* __restrict__ bias,
                 const float* __restrict__ mixw, float* __restrict__ part)
{
  __shared__ char smem[65536];                    // 2 x {A[2][128][32], B[2][128][32]}
  const int tid  = threadIdx.x;
  const int lane = tid & 63, wid = tid >> 6;
  const int wm = wid >> 2, wn = wid & 3;          // 2M x 4N waves, 64x32 each
  const int lr = lane & 15, lg = lane >> 4;

  const int bid = blockIdx.x;
  const int xcd = bid & 7, j = bid >> 3;
  const int tm  = (xcd << 3) | (j & 7);           // 0..63
  const int tn  = j >> 3;                         // 0..7

  const int bt  = tm >> 4;                        // batch
  const int sl0 = (tm & 15) << 7;                 // batch-local s base of block

  // A-staging mapping: e-col = tid&63, s-quad group = tid>>6 (16 s each)
  const int ae  = tid & 63;
  const int asq = tid >> 6;
  const float* xbase = x + ((long)bt * E_ + ae) * S_ + sl0 + asq * 16;
  // B-staging mapping: c-row = tid>>2, 16-e span = (tid&3)*16
  const int bc  = tid >> 2;
  const int beq = tid & 3;
  const float* wbase = W1 + (long)(tn * 128 + bc) * E_ + beq * 16;

  float4 ax[4], bx[4];
  auto loadAB = [&](int t) {
    const float* pa = xbase + (long)t * 64 * S_;
    const float* pb = wbase + t * 64;
#pragma unroll
    for (int i = 0; i < 4; ++i) ax[i] = *(const float4*)(pa + i * 4);
#pragma unroll
    for (int i = 0; i < 4; ++i) bx[i] = *(const float4*)(pb + i * 4);
  };
  auto cvtwrite = [&](char* buf) {
    // A: transpose-scatter, 16 u16 writes (2-way bank alias)
#pragma unroll
    for (int i = 0; i < 4; ++i) {
      float v0 = ax[i].x, v1 = ax[i].y, v2 = ax[i].z, v3 = ax[i].w;
      int half = ae >> 5, colb = (ae & 31) * 2;
#pragma unroll
      for (int jj = 0; jj < 4; ++jj) {
        int srow = asq * 16 + i * 4 + jj;
        float vv = jj == 0 ? v0 : jj == 1 ? v1 : jj == 2 ? v2 : v3;
        *(unsigned short*)(buf + half * 8192 + srow * 64 + (colb ^ SWZ(srow))) = f2bf(vv);
      }
    }
    // B: 16 bf16 contiguous in k -> 2 ds_write_b128 (B region = buf+16384)
    u16x8 bv[2];
#pragma unroll
    for (int i = 0; i < 4; ++i) {
      bv[i >> 1][(i & 1) * 4 + 0] = f2bf(bx[i].x);
      bv[i >> 1][(i & 1) * 4 + 1] = f2bf(bx[i].y);
      bv[i >> 1][(i & 1) * 4 + 2] = f2bf(bx[i].z);
      bv[i >> 1][(i & 1) * 4 + 3] = f2bf(bx[i].w);
    }
    int half = beq >> 1, colb = (beq & 1) * 32;
    int base = 16384 + half * 8192 + bc * 64;
#pragma unroll
    for (int u = 0; u < 2; ++u)
      *(u16x8*)(buf + base + ((colb + u * 16) ^ SWZ(bc))) = bv[u];
  };

  f32x4 acc[4][2] = {};

  // Prologue
  loadAB(0);
  cvtwrite(smem);
  loadAB(1);
  __syncthreads();

  for (int t = 0; t < 16; ++t) {
    char* cur = smem + (t & 1) * 32768;
    char* nxt = smem + ((t + 1) & 1) * 32768;
    if (t < 15) cvtwrite(nxt);                    // regs hold tile t+1
    if (t < 14) loadAB(t + 2);                    // issue early
#pragma unroll
    for (int ks = 0; ks < 2; ++ks) {
      bf16x8 af[4], bfv[2];
#pragma unroll
      for (int mf = 0; mf < 4; ++mf) {
        int row = wm * 64 + mf * 16 + lr;
        af[mf] = *(const bf16x8*)(cur + ks * 8192 + row * 64 + ((lg * 16) ^ SWZ(row)));
      }
#pragma unroll
      for (int nf = 0; nf < 2; ++nf) {
        int row = wn * 32 + nf * 16 + lr;
        bfv[nf] = *(const bf16x8*)(cur + 16384 + ks * 8192 + row * 64 + ((lg * 16) ^ SWZ(row)));
      }
#pragma unroll
      for (int mf = 0; mf < 4; ++mf)
#pragma unroll
        for (int nf = 0; nf < 2; ++nf)
          acc[mf][nf] = __builtin_amdgcn_mfma_f32_16x16x32_bf16(
              af[mf], bfv[nf], acc[mf][nf], 0, 0, 0);
    }
    __syncthreads();
  }

  // Epilogue: Yt + scan partials. C/D frag: col=lane&15, row=(lane>>4)*4+j
  const int sb = sl0 + wm * 64;
  const int ch = ((tm & 15) << 1) + wm;
#pragma unroll
  for (int nf = 0; nf < 2; ++nf) {
    const int c = tn * 128 + wn * 32 + nf * 16 + lr;
    const float bv = bias[c];
    const int h = c >> 6;
    float sm = 0.f;
#pragma unroll
    for (int mf = 0; mf < 4; ++mf) {
#pragma unroll
      for (int jj = 0; jj < 4; ++jj) {
        const int sl = sb + mf * 16 + lg * 4 + jj;
        float v = acc[mf][nf][jj] + bv;
        Yt[((long)bt * S_ + sl) * E_ + c] = f2bf(v);
        sm += (h < 8) ? v : v * mixw[h * S_ + sl];
      }
    }
    sm += __shfl_xor(sm, 16, 64);
    sm += __shfl_xor(sm, 32, 64);
    if (lg == 0) part[((long)bt * NCH + ch) * E_ + c] = sm;
  }
}

// ---------------------------------------------------------------------------
// GEMM2 (fused W-convert): out(b,e,s) = transposed-write of Zt * W2_bf16^T
// A = Zt bf16 via global_load_lds; B staged from W2 fp32 in regs.
// Per-buffer layout: A [0,16384), B [16384,32768).
// ---------------------------------------------------------------------------
__device__ __forceinline__ void stage_halfA(char* lds, const unsigned short* __restrict__ base,
                                            int kt, int ks, int tid) {
  int row = tid >> 2;
  int cb  = (tid & 3) << 4;
  int cbs = cb ^ SWZ(row);
  const unsigned short* src = base + (long)row * K_ + kt + ks * 32 + (cbs >> 1);
  __builtin_amdgcn_global_load_lds((const AS1 void*)src,
      (AS3 void*)(lds + ks * 8192 + tid * 16), 16, 0, 0);
}

__global__ __launch_bounds__(512, 4)
void gemm2_fused(const unsigned short* __restrict__ Zt, const float* __restrict__ W2,
                 float* __restrict__ out, const float* __restrict__ bias)
{
  __shared__ char smem[65536];
  const int tid  = threadIdx.x;
  const int lane = tid & 63, wid = tid >> 6;
  const int wm = wid >> 2, wn = wid & 3;
  const int lr = lane & 15, lg = lane >> 4;

  const int bid = blockIdx.x;
  const int xcd = bid & 7, j = bid >> 3;
  const int tm  = (xcd << 3) | (j & 7);
  const int tn  = j >> 3;

  const unsigned short* Ab = Zt + (long)tm * 128 * K_;
  const int bc  = tid >> 2;
  const int beq = tid & 3;
  const float* wbase = W2 + (long)(tn * 128 + bc) * E_ + beq * 16;

  float4 bx[4];
  auto loadB = [&](int t) {
    const float* pb = wbase + t * 64;
#pragma unroll
    for (int i = 0; i < 4; ++i) bx[i] = *(const float4*)(pb + i * 4);
  };
  auto cvtwriteB = [&](char* buf) {
    u16x8 bv[2];
#pragma unroll
    for (int i = 0; i < 4; ++i) {
      bv[i >> 1][(i & 1) * 4 + 0] = f2bf(bx[i].x);
      bv[i >> 1][(i & 1) * 4 + 1] = f2bf(bx[i].y);
      bv[i >> 1][(i & 1) * 4 + 2] = f2bf(bx[i].z);
      bv[i >> 1][(i & 1) * 4 + 3] = f2bf(bx[i].w);
    }
    int half = beq >> 1, colb = (beq & 1) * 32;
    int base = 16384 + half * 8192 + bc * 64;
#pragma unroll
    for (int u = 0; u < 2; ++u)
      *(u16x8*)(buf + base + ((colb + u * 16) ^ SWZ(bc))) = bv[u];
  };

  f32x4 acc[4][2] = {};

  // Prologue
  loadB(0);
  stage_halfA(smem, Ab, 0, 0, tid);
  stage_halfA(smem, Ab, 0, 1, tid);
  cvtwriteB(smem);
  loadB(1);
  __syncthreads();

  for (int t = 0; t < 16; ++t) {
    char* cur = smem + (t & 1) * 32768;
    char* nxt = smem + ((t + 1) & 1) * 32768;
    if (t < 15) {
      stage_halfA(nxt, Ab, (t + 1) * 64, 0, tid);
      stage_halfA(nxt, Ab, (t + 1) * 64, 1, tid);
      cvtwriteB(nxt);
    }
    if (t < 14) loadB(t + 2);
#pragma unroll
    for (int ks = 0; ks < 2; ++ks) {
      bf16x8 af[4], bfv[2];
#pragma unroll
      for (int mf = 0; mf < 4; ++mf) {
        int row = wm * 64 + mf * 16 + lr;
        af[mf] = *(const bf16x8*)(cur + ks * 8192 + row * 64 + ((lg * 16) ^ SWZ(row)));
      }
#pragma unroll
      for (int nf = 0; nf < 2; ++nf) {
        int row = wn * 32 + nf * 16 + lr;
        bfv[nf] = *(const bf16x8*)(cur + 16384 + ks * 8192 + row * 64 + ((lg * 16) ^ SWZ(row)));
      }
#pragma unroll
      for (int mf = 0; mf < 4; ++mf)
#pragma unroll
        for (int nf = 0; nf < 2; ++nf)
          acc[mf][nf] = __builtin_amdgcn_mfma_f32_16x16x32_bf16(
              af[mf], bfv[nf], acc[mf][nf], 0, 0, 0);
    }
    __syncthreads();
  }

  // Epilogue: transposed fp32 write into (B_,E_,S_)
#pragma unroll
  for (int nf = 0; nf < 2; ++nf) {
    const int c = tn * 128 + wn * 32 + nf * 16 + lr;
    const float bv = bias[c];
#pragma unroll
    for (int mf = 0; mf < 4; ++mf) {
      const int r0 = tm * 128 + wm * 64 + mf * 16 + lg * 4;
      const int s = r0 & (S_ - 1);
      const int b = r0 >> 11;
      float4 v;
      v.x = acc[mf][nf][0] + bv; v.y = acc[mf][nf][1] + bv;
      v.z = acc[mf][nf][2] + bv; v.w = acc[mf][nf][3] + bv;
      *(float4*)(out + ((long)b * E_ + c) * S_ + s) = v;
    }
  }
}

// ---------------------------------------------------------------------------
// scan_final: causal prefix combine using chunk partials from GEMM1 epilogue.
//   h < 8 : z[s,c] = mix_w[h,s] * (prior-chunk sums + intra-chunk cumsum)
//   h >= 8: z[s,c] = (prior weighted sums + intra-chunk weighted cumsum)
// ---------------------------------------------------------------------------
__global__ __launch_bounds__(256)
void scan_final(const unsigned short* __restrict__ yt, const float* __restrict__ mixw,
                const float* __restrict__ mixb, const float* __restrict__ part,
                unsigned short* __restrict__ zt)
{
  const int b  = blockIdx.z;
  const int c  = blockIdx.y * 256 + threadIdx.x;
  const int ch = blockIdx.x;
  const int h  = c >> 6;
  float acc = 0.f;
  for (int p = 0; p < ch; ++p) acc += part[((long)b * NCH + p) * E_ + c];
  const unsigned short* yp = yt + ((long)b * S_ + ch * CS) * E_ + c;
  unsigned short*       zp = zt + ((long)b * S_ + ch * CS) * E_ + c;
  const float* mw = mixw + (long)h * S_ + ch * CS;
  const float* mb = mixb + (long)h * S_ + ch * CS;
  if (h < 8) {
    for (int s = 0; s < CS; ++s) {
      acc += bf2f(yp[(long)s * E_]);
      zp[(long)s * E_] = f2bf(fmaf(acc, mw[s], mb[s]));
    }
  } else {
    for (int s = 0; s < CS; ++s) {
      acc += bf2f(yp[(long)s * E_]) * mw[s];
      zp[(long)s * E_] = f2bf(acc + mb[s]);
    }
  }
}

// ---------------------------------------------------------------------------
extern "C" void kernel_launch(void* const* d_in, const int* in_sizes, int n_in,
                              void* d_out, int out_size, void* d_ws, size_t ws_size,
                              hipStream_t stream)
{
  (void)in_sizes; (void)n_in; (void)out_size; (void)ws_size;
  const float* x     = (const float*)d_in[0];
  const float* in_w  = (const float*)d_in[1];
  const float* in_b  = (const float*)d_in[2];
  const float* out_w = (const float*)d_in[3];
  const float* out_b = (const float*)d_in[4];
  const float* mix_w = (const float*)d_in[5];
  const float* mix_b = (const float*)d_in[6];

  char* ws = (char*)d_ws;
  unsigned short* Yt  = (unsigned short*)(ws);                            // 16 MB
  unsigned short* Zt  = (unsigned short*)(ws + (size_t)16 * 1024 * 1024); // 16 MB
  float*          part = (float*)(ws + (size_t)32 * 1024 * 1024);         // 512 KB

  // in_proj (+transpose +convert) + fused scan partials
  gemm1_fused<<<dim3(512), 512, 0, stream>>>(x, in_w, Yt, in_b, mix_w, part);

  scan_final<<<dim3(NCH, E_ / 256, B_), 256, 0, stream>>>(Yt, mix_w, mix_b, part, Zt);

  // out_proj (+convert): out(b,e,s) = transposed-write of Zt * W2^T + out_b
  gemm2_fused<<<dim3(512), 512, 0, stream>>>(Zt, out_w, (float*)d_out, out_b);
}